// Round 2
// baseline (8741.856 us; speedup 1.0000x reference)
//
#include <hip/hip_runtime.h>
#include <hip/hip_bf16.h>

// Dims fixed by the reference: B=64, T=512, D=512, H=512, 3H=1536.
// Inputs/outputs are float32 (per reference); MFMA operands are bf16.
#define B_ 64
#define T_ 512
#define D_ 512
#define H_ 512
#define G3 1536

typedef float f32x4 __attribute__((ext_vector_type(4)));
typedef __bf16 bf16x8 __attribute__((ext_vector_type(8)));

// LDS row pitch (bf16 elems) for BK=32 tiles: 56 elems = 112 B.
#define LDSP 56

union bfpack { bf16x8 v; __hip_bfloat16 h[8]; };

__device__ inline bf16x8 cvt8(const float* __restrict__ p) {
    float4 f0 = *(const float4*)p;
    float4 f1 = *(const float4*)(p + 4);
    bfpack u;
    u.h[0] = __float2bfloat16(f0.x); u.h[1] = __float2bfloat16(f0.y);
    u.h[2] = __float2bfloat16(f0.z); u.h[3] = __float2bfloat16(f0.w);
    u.h[4] = __float2bfloat16(f1.x); u.h[5] = __float2bfloat16(f1.y);
    u.h[6] = __float2bfloat16(f1.z); u.h[7] = __float2bfloat16(f1.w);
    return u.v;
}

// ---------------- KW: w_hh fp32 -> bf16 copy (once per call) -----------------
__global__ void kw_cvt(const float* __restrict__ W, __hip_bfloat16* __restrict__ Wb) {
    int i = blockIdx.x * blockDim.x + threadIdx.x;
    if (i < G3 * H_) Wb[i] = __float2bfloat16(W[i]);
}

// ---------------- K0: init h state buffers -----------------------------------
__global__ void k0_init_h(const float* __restrict__ h_in,
                          __hip_bfloat16* __restrict__ hb,
                          float* __restrict__ hf) {
    int i = blockIdx.x * blockDim.x + threadIdx.x;
    if (i < B_ * H_) {
        float v = h_in[i];
        hb[i] = __float2bfloat16(v);
        hf[i] = v;
    }
}

// ---------------- K1: x_gates = x @ w_ih^T + b_ih  (MFMA, 128x128 tile) ------
// A = x [M=32768, K=512] fp32 row-major (m = b*512+t), B = w_ih [N=1536, K=512]
// fp32 row-major (B^T form). fp32->bf16 conversion happens during LDS staging.
// Output time-major bf16: XG[t][b][n].
__global__ __launch_bounds__(256) void k1_xgemm(
    const float* __restrict__ X,
    const float* __restrict__ W,
    const float* __restrict__ bias,
    __hip_bfloat16* __restrict__ XG)
{
    __shared__ __align__(16) __hip_bfloat16 la[128 * LDSP];
    __shared__ __align__(16) __hip_bfloat16 lb[128 * LDSP];
    int tid = threadIdx.x;
    int bx  = blockIdx.x;
    int m0 = (bx / 12) * 128;
    int n0 = (bx % 12) * 128;
    int wave = tid >> 6, lane = tid & 63;
    int wh = wave >> 1, ww = wave & 1;   // 2x2 wave grid, each wave 64x64
    int l15 = lane & 15, kq = lane >> 4; // kq in 0..3

    f32x4 acc[4][4];
    #pragma unroll
    for (int i = 0; i < 4; i++)
        #pragma unroll
        for (int j = 0; j < 4; j++) acc[i][j] = (f32x4){0.f, 0.f, 0.f, 0.f};

    for (int kt = 0; kt < 16; ++kt) {
        int k0 = kt * 32;
        for (int s = tid; s < 512; s += 256) {
            int r = s >> 2, c = s & 3;
            *(bf16x8*)&la[r * LDSP + c * 8] =
                cvt8(&X[(size_t)(m0 + r) * D_ + k0 + c * 8]);
            *(bf16x8*)&lb[r * LDSP + c * 8] =
                cvt8(&W[(size_t)(n0 + r) * D_ + k0 + c * 8]);
        }
        __syncthreads();
        bf16x8 af[4], bq[4];
        #pragma unroll
        for (int i = 0; i < 4; i++)
            af[i] = *(const bf16x8*)&la[(wh * 64 + i * 16 + l15) * LDSP + kq * 8];
        #pragma unroll
        for (int j = 0; j < 4; j++)
            bq[j] = *(const bf16x8*)&lb[(ww * 64 + j * 16 + l15) * LDSP + kq * 8];
        #pragma unroll
        for (int i = 0; i < 4; i++)
            #pragma unroll
            for (int j = 0; j < 4; j++)
                acc[i][j] = __builtin_amdgcn_mfma_f32_16x16x32_bf16(
                    af[i], bq[j], acc[i][j], 0, 0, 0);
        __syncthreads();
    }
    // epilogue: C row = (lane>>4)*4 + reg, col = lane&15 (m89-verified layout)
    #pragma unroll
    for (int i = 0; i < 4; i++) {
        #pragma unroll
        for (int j = 0; j < 4; j++) {
            #pragma unroll
            for (int r = 0; r < 4; r++) {
                int m = m0 + wh * 64 + i * 16 + kq * 4 + r;
                int n = n0 + ww * 64 + j * 16 + l15;
                int b = m >> 9, t = m & 511;
                float v = acc[i][j][r] + bias[n];
                XG[((size_t)t * B_ + b) * G3 + n] = __float2bfloat16(v);
            }
        }
    }
}

// ---------------- K2: h_gates = h @ w_hh^T + b_hh  (64x1536, K=512) ----------
// 12 blocks x 128 cols; 4 waves, wave w owns cols [w*32, w*32+32), all 64 rows.
__global__ __launch_bounds__(256) void k2_hgemm(
    const __hip_bfloat16* __restrict__ Hb,   // [64,512] current h (bf16)
    const __hip_bfloat16* __restrict__ W,    // w_hh bf16 copy [1536,512]
    const float* __restrict__ bias,          // b_hh fp32
    float* __restrict__ HG)                  // [64,1536] fp32
{
    __shared__ __align__(16) __hip_bfloat16 la[64 * LDSP];
    __shared__ __align__(16) __hip_bfloat16 lb[128 * LDSP];
    int tid = threadIdx.x;
    int n0 = blockIdx.x * 128;
    int wave = tid >> 6, lane = tid & 63;
    int l15 = lane & 15, kq = lane >> 4;

    f32x4 acc[4][2];
    #pragma unroll
    for (int i = 0; i < 4; i++)
        #pragma unroll
        for (int j = 0; j < 2; j++) acc[i][j] = (f32x4){0.f, 0.f, 0.f, 0.f};

    for (int kt = 0; kt < 16; ++kt) {
        int k0 = kt * 32;
        {   // A: 64 rows x 32 cols = 256 16B-chunks, 1 per thread
            int r = tid >> 2, c = tid & 3;
            *(uint4*)&la[r * LDSP + c * 8] =
                *(const uint4*)&Hb[(size_t)r * H_ + k0 + c * 8];
        }
        for (int s = tid; s < 512; s += 256) { // B: 128 rows x 32 cols
            int r = s >> 2, c = s & 3;
            *(uint4*)&lb[r * LDSP + c * 8] =
                *(const uint4*)&W[(size_t)(n0 + r) * H_ + k0 + c * 8];
        }
        __syncthreads();
        bf16x8 af[4], bq[2];
        #pragma unroll
        for (int i = 0; i < 4; i++)
            af[i] = *(const bf16x8*)&la[(i * 16 + l15) * LDSP + kq * 8];
        #pragma unroll
        for (int j = 0; j < 2; j++)
            bq[j] = *(const bf16x8*)&lb[(wave * 32 + j * 16 + l15) * LDSP + kq * 8];
        #pragma unroll
        for (int i = 0; i < 4; i++)
            #pragma unroll
            for (int j = 0; j < 2; j++)
                acc[i][j] = __builtin_amdgcn_mfma_f32_16x16x32_bf16(
                    af[i], bq[j], acc[i][j], 0, 0, 0);
        __syncthreads();
    }
    #pragma unroll
    for (int i = 0; i < 4; i++)
        #pragma unroll
        for (int j = 0; j < 2; j++)
            #pragma unroll
            for (int r = 0; r < 4; r++) {
                int m = i * 16 + kq * 4 + r;
                int n = n0 + wave * 32 + j * 16 + l15;
                HG[(size_t)m * G3 + n] = acc[i][j][r] + bias[n];
            }
}

// ---------------- K3: per-sample LN x3 + gating + h update -------------------
__device__ inline float2 breduce(float s, float ss, float* red) {
    #pragma unroll
    for (int off = 32; off > 0; off >>= 1) {
        s  += __shfl_down(s, off, 64);
        ss += __shfl_down(ss, off, 64);
    }
    int wave = threadIdx.x >> 6, lane = threadIdx.x & 63;
    if (lane == 0) { red[wave] = s; red[4 + wave] = ss; }
    __syncthreads();
    float S  = red[0] + red[1] + red[2] + red[3];
    float SS = red[4] + red[5] + red[6] + red[7];
    __syncthreads();
    return make_float2(S, SS);
}

__global__ __launch_bounds__(256) void k3_pointwise(
    const __hip_bfloat16* __restrict__ XG, const float* __restrict__ HG,
    __hip_bfloat16* __restrict__ hb, float* __restrict__ hf,
    const float* __restrict__ lnrw, const float* __restrict__ lnrb,
    const float* __restrict__ lnzw, const float* __restrict__ lnzb,
    const float* __restrict__ lnnw, const float* __restrict__ lnnb,
    float* __restrict__ out, int t)
{
    __shared__ float red[8];
    int b = blockIdx.x, tid = threadIdx.x;
    const __hip_bfloat16* xr = XG + ((size_t)t * B_ + b) * G3;
    const float* hr = HG + (size_t)b * G3;
    int j0 = tid, j1 = tid + 256;
    const float inv = 1.0f / 512.0f;

    // r gate
    float a0 = __bfloat162float(xr[j0]) + hr[j0];
    float a1 = __bfloat162float(xr[j1]) + hr[j1];
    float2 s = breduce(a0 + a1, a0 * a0 + a1 * a1, red);
    float mean = s.x * inv, var = s.y * inv - mean * mean;
    float rstd = rsqrtf(var + 1e-5f);
    float r0 = 1.f / (1.f + __expf(-((a0 - mean) * rstd * lnrw[j0] + lnrb[j0])));
    float r1 = 1.f / (1.f + __expf(-((a1 - mean) * rstd * lnrw[j1] + lnrb[j1])));

    // z gate
    float b0 = __bfloat162float(xr[512 + j0]) + hr[512 + j0];
    float b1 = __bfloat162float(xr[512 + j1]) + hr[512 + j1];
    s = breduce(b0 + b1, b0 * b0 + b1 * b1, red);
    mean = s.x * inv; var = s.y * inv - mean * mean; rstd = rsqrtf(var + 1e-5f);
    float z0 = 1.f / (1.f + __expf(-((b0 - mean) * rstd * lnzw[j0] + lnzb[j0])));
    float z1 = 1.f / (1.f + __expf(-((b1 - mean) * rstd * lnzw[j1] + lnzb[j1])));

    // n gate (uses r)
    float c0 = __bfloat162float(xr[1024 + j0]) + r0 * hr[1024 + j0];
    float c1 = __bfloat162float(xr[1024 + j1]) + r1 * hr[1024 + j1];
    s = breduce(c0 + c1, c0 * c0 + c1 * c1, red);
    mean = s.x * inv; var = s.y * inv - mean * mean; rstd = rsqrtf(var + 1e-5f);
    float n0 = tanhf((c0 - mean) * rstd * lnnw[j0] + lnnb[j0]);
    float n1 = tanhf((c1 - mean) * rstd * lnnw[j1] + lnnb[j1]);

    // h update: carry path kept in fp32; bf16 shadow feeds next step's GEMM
    float h0 = hf[b * H_ + j0], h1 = hf[b * H_ + j1];
    float hn0 = (1.f - z0) * n0 + z0 * h0;
    float hn1 = (1.f - z1) * n1 + z1 * h1;
    hf[b * H_ + j0] = hn0; hf[b * H_ + j1] = hn1;
    hb[b * H_ + j0] = __float2bfloat16(hn0);
    hb[b * H_ + j1] = __float2bfloat16(hn1);
    out[((size_t)b * T_ + t) * H_ + j0] = hn0;
    out[((size_t)b * T_ + t) * H_ + j1] = hn1;
    if (t == T_ - 1) {
        out[(size_t)B_ * T_ * H_ + b * H_ + j0] = hn0;
        out[(size_t)B_ * T_ * H_ + b * H_ + j1] = hn1;
    }
}

extern "C" void kernel_launch(void* const* d_in, const int* in_sizes, int n_in,
                              void* d_out, int out_size, void* d_ws, size_t ws_size,
                              hipStream_t stream)
{
    const float* x    = (const float*)d_in[0];
    const float* h    = (const float*)d_in[1];
    const float* w_ih = (const float*)d_in[2];
    const float* b_ih = (const float*)d_in[3];
    const float* w_hh = (const float*)d_in[4];
    const float* b_hh = (const float*)d_in[5];
    const float* lnrw = (const float*)d_in[6];
    const float* lnrb = (const float*)d_in[7];
    const float* lnzw = (const float*)d_in[8];
    const float* lnzb = (const float*)d_in[9];
    const float* lnnw = (const float*)d_in[10];
    const float* lnnb = (const float*)d_in[11];
    float* out = (float*)d_out;

    // ws layout (bytes), all offsets 16B-aligned:
    //   XG  bf16 [512][64][1536] = 100,663,296   @ 0
    //   WHB bf16 [1536][512]     =   1,572,864   @ 100,663,296
    //   HG  f32  [64][1536]      =     393,216   @ 102,236,160
    //   HB  bf16 [64][512]       =      65,536   @ 102,629,376
    //   HF  f32  [64][512]       =     131,072   @ 102,694,912
    // total ~98 MB
    char* ws = (char*)d_ws;
    __hip_bfloat16* XG  = (__hip_bfloat16*)ws;
    __hip_bfloat16* WHB = (__hip_bfloat16*)(ws + 100663296);
    float*          HG  = (float*)(ws + 102236160);
    __hip_bfloat16* HB  = (__hip_bfloat16*)(ws + 102629376);
    float*          HF  = (float*)(ws + 102694912);

    kw_cvt<<<3072, 256, 0, stream>>>(w_hh, WHB);
    k0_init_h<<<128, 256, 0, stream>>>(h, HB, HF);
    k1_xgemm<<<3072, 256, 0, stream>>>(x, w_ih, b_ih, XG);
    for (int t = 0; t < T_; ++t) {
        k2_hgemm<<<12, 256, 0, stream>>>(HB, WHB, b_hh, HG);
        k3_pointwise<<<64, 256, 0, stream>>>(XG, HG, HB, HF,
            lnrw, lnrb, lnzw, lnzb, lnnw, lnnb, out, t);
    }
}

// Round 3
// 5607.143 us; speedup vs baseline: 1.5591x; 1.5591x over previous
//
#include <hip/hip_runtime.h>
#include <hip/hip_bf16.h>

// B=64, T=512, D=512, H=512, 3H=1536. fp32 I/O; bf16 MFMA operands.
#define B_ 64
#define T_ 512
#define D_ 512
#define H_ 512
#define G3 1536
#define NBLK 16          // persistent blocks: 96 gate-cols + 4 samples each

typedef float f32x4 __attribute__((ext_vector_type(4)));
typedef __bf16 bf16x8 __attribute__((ext_vector_type(8)));

#define LDSP 56          // k1 LDS pitch
#define WPITCH 520       // persistent-kernel w-slice pitch (bf16 elems): breaks bank conflicts

union bfpack { bf16x8 v; __hip_bfloat16 h[8]; };

__device__ inline bf16x8 cvt8(const float* __restrict__ p) {
    float4 f0 = *(const float4*)p;
    float4 f1 = *(const float4*)(p + 4);
    bfpack u;
    u.h[0] = __float2bfloat16(f0.x); u.h[1] = __float2bfloat16(f0.y);
    u.h[2] = __float2bfloat16(f0.z); u.h[3] = __float2bfloat16(f0.w);
    u.h[4] = __float2bfloat16(f1.x); u.h[5] = __float2bfloat16(f1.y);
    u.h[6] = __float2bfloat16(f1.z); u.h[7] = __float2bfloat16(f1.w);
    return u.v;
}

// ---------------- K0: init HB (h bf16) + zero barrier counters ---------------
__global__ void k0_init(const float* __restrict__ h_in,
                        __hip_bfloat16* __restrict__ hb,
                        unsigned int* __restrict__ ctr) {
    int i = blockIdx.x * blockDim.x + threadIdx.x;
    if (i < B_ * H_) hb[i] = __float2bfloat16(h_in[i]);
    if (i < 1024)    ctr[i] = 0u;
}

// ---------------- K1: XG = x @ w_ih^T + b_ih (MFMA 128x128, bf16 out) --------
__global__ __launch_bounds__(256) void k1_xgemm(
    const float* __restrict__ X, const float* __restrict__ W,
    const float* __restrict__ bias, __hip_bfloat16* __restrict__ XG)
{
    __shared__ __align__(16) __hip_bfloat16 la[128 * LDSP];
    __shared__ __align__(16) __hip_bfloat16 lb[128 * LDSP];
    int tid = threadIdx.x, bx = blockIdx.x;
    int m0 = (bx / 12) * 128, n0 = (bx % 12) * 128;
    int wave = tid >> 6, lane = tid & 63;
    int wh = wave >> 1, ww = wave & 1;
    int l15 = lane & 15, kq = lane >> 4;

    f32x4 acc[4][4];
    #pragma unroll
    for (int i = 0; i < 4; i++)
        #pragma unroll
        for (int j = 0; j < 4; j++) acc[i][j] = (f32x4){0.f, 0.f, 0.f, 0.f};

    for (int kt = 0; kt < 16; ++kt) {
        int k0 = kt * 32;
        for (int s = tid; s < 512; s += 256) {
            int r = s >> 2, c = s & 3;
            *(bf16x8*)&la[r * LDSP + c * 8] = cvt8(&X[(size_t)(m0 + r) * D_ + k0 + c * 8]);
            *(bf16x8*)&lb[r * LDSP + c * 8] = cvt8(&W[(size_t)(n0 + r) * D_ + k0 + c * 8]);
        }
        __syncthreads();
        bf16x8 af[4], bq[4];
        #pragma unroll
        for (int i = 0; i < 4; i++)
            af[i] = *(const bf16x8*)&la[(wh * 64 + i * 16 + l15) * LDSP + kq * 8];
        #pragma unroll
        for (int j = 0; j < 4; j++)
            bq[j] = *(const bf16x8*)&lb[(ww * 64 + j * 16 + l15) * LDSP + kq * 8];
        #pragma unroll
        for (int i = 0; i < 4; i++)
            #pragma unroll
            for (int j = 0; j < 4; j++)
                acc[i][j] = __builtin_amdgcn_mfma_f32_16x16x32_bf16(af[i], bq[j], acc[i][j], 0, 0, 0);
        __syncthreads();
    }
    #pragma unroll
    for (int i = 0; i < 4; i++)
        #pragma unroll
        for (int j = 0; j < 4; j++)
            #pragma unroll
            for (int r = 0; r < 4; r++) {
                int m = m0 + wh * 64 + i * 16 + kq * 4 + r;
                int n = n0 + ww * 64 + j * 16 + l15;
                int b = m >> 9, t = m & 511;
                XG[((size_t)t * B_ + b) * G3 + n] = __float2bfloat16(acc[i][j][r] + bias[n]);
            }
}

// ---------------- K2: persistent recurrence kernel ---------------------------
// 16 blocks x 512 threads. Block i: GEMM cols [96i,96i+96) of HG; pointwise
// samples [4i,4i+4). w_hh slice bf16 LDS-resident across all 512 steps.
// Per step: GEMM -> barrier(2t) -> pointwise -> barrier(2t+1).
__global__ __launch_bounds__(512, 1) void k2_recur(
    const float* __restrict__ h_in, const float* __restrict__ Whh,
    const float* __restrict__ b_hh,
    const float* __restrict__ lnrw, const float* __restrict__ lnrb,
    const float* __restrict__ lnzw, const float* __restrict__ lnzb,
    const float* __restrict__ lnnw, const float* __restrict__ lnnb,
    const __hip_bfloat16* __restrict__ XG,
    float* __restrict__ HG, __hip_bfloat16* __restrict__ HB,
    unsigned int* __restrict__ ctr, float* __restrict__ out)
{
    __shared__ __align__(16) __hip_bfloat16 lw[96 * WPITCH]; // 99,840 B
    __shared__ float sc[32];

    const int tid = threadIdx.x;
    const int blk = blockIdx.x;
    const int n0 = blk * 96;   // gate-column slice base
    const int s0 = blk * 4;    // pointwise sample base

    // --- one-time: stage w_hh slice fp32->bf16 into LDS (pitch WPITCH) ---
    for (int idx = tid; idx < 96 * 64; idx += 512) {
        int row = idx >> 6, ch = idx & 63;
        *(bf16x8*)&lw[row * WPITCH + ch * 8] = cvt8(&Whh[(size_t)(n0 + row) * H_ + ch * 8]);
    }

    // --- GEMM wave roles ---
    const int w = tid >> 6, lane = tid & 63;
    const int l15 = lane & 15, kq = lane >> 4;
    const int mt = w >> 1;             // m-tile 0..3 (rows mt*16+l15)
    const int nj0 = (w & 1) * 3;       // 3 n-tiles per wave

    // --- pointwise roles: sample sid, 4 cols each ---
    const int sid = tid >> 7;          // 0..3
    const int c = tid & 127;           // col base; cols c+128j
    const int b = s0 + sid;

    // per-thread constant preloads (stay in regs across the t-loop)
    float bhr[4], bhz[4], bhn[4], wr[4], br_[4], wz[4], bz_[4], wn[4], bn_[4], hf[4];
    #pragma unroll
    for (int j = 0; j < 4; j++) {
        int col = c + j * 128;
        bhr[j] = b_hh[col];       bhz[j] = b_hh[512 + col]; bhn[j] = b_hh[1024 + col];
        wr[j] = lnrw[col]; br_[j] = lnrb[col];
        wz[j] = lnzw[col]; bz_[j] = lnzb[col];
        wn[j] = lnnw[col]; bn_[j] = lnnb[col];
        hf[j] = h_in[b * H_ + col];   // fp32 h shadow (this block owns sample b)
    }
    __syncthreads();

    const float inv = 1.0f / 512.0f;

    for (int t = 0; t < T_; ++t) {
        // ================= GEMM phase: HG slice = h @ w_slice^T ==============
        bf16x8 afr[16];
        {
            const __hip_bfloat16* hrow = HB + (mt * 16 + l15) * H_ + kq * 8;
            #pragma unroll
            for (int kt = 0; kt < 16; kt++) afr[kt] = *(const bf16x8*)(hrow + kt * 32);
        }
        f32x4 a0 = {0,0,0,0}, a1 = {0,0,0,0}, a2 = {0,0,0,0};
        #pragma unroll
        for (int kt = 0; kt < 16; kt++) {
            bf16x8 b0 = *(const bf16x8*)&lw[((nj0    ) * 16 + l15) * WPITCH + kt * 32 + kq * 8];
            bf16x8 b1 = *(const bf16x8*)&lw[((nj0 + 1) * 16 + l15) * WPITCH + kt * 32 + kq * 8];
            bf16x8 b2 = *(const bf16x8*)&lw[((nj0 + 2) * 16 + l15) * WPITCH + kt * 32 + kq * 8];
            a0 = __builtin_amdgcn_mfma_f32_16x16x32_bf16(afr[kt], b0, a0, 0, 0, 0);
            a1 = __builtin_amdgcn_mfma_f32_16x16x32_bf16(afr[kt], b1, a1, 0, 0, 0);
            a2 = __builtin_amdgcn_mfma_f32_16x16x32_bf16(afr[kt], b2, a2, 0, 0, 0);
        }
        {
            int rowb = mt * 16 + kq * 4;
            int colb = n0 + nj0 * 16 + l15;
            #pragma unroll
            for (int r = 0; r < 4; r++) {
                HG[(rowb + r) * G3 + colb     ] = a0[r];
                HG[(rowb + r) * G3 + colb + 16] = a1[r];
                HG[(rowb + r) * G3 + colb + 32] = a2[r];
            }
        }
        // ---- barrier A: all HG slices visible (agent scope) ----
        __syncthreads();   // drains vmcnt before barrier -> stores in L2
        if (tid == 0) {
            __threadfence();  // L2 writeback to LLC
            __hip_atomic_fetch_add(&ctr[2 * t], 1u, __ATOMIC_RELEASE, __HIP_MEMORY_SCOPE_AGENT);
            while (__hip_atomic_load(&ctr[2 * t], __ATOMIC_ACQUIRE, __HIP_MEMORY_SCOPE_AGENT) < NBLK) {}
            __threadfence();  // invalidate stale L1/L2 lines
        }
        __syncthreads();

        // ================= pointwise: LN x3 + gating for samples s0..s0+3 ====
        const float* hgrow = HG + (size_t)b * G3;
        const __hip_bfloat16* xgrow = XG + ((size_t)t * B_ + b) * G3;
        float ar[4], az[4], hgn[4], xn[4];
        float sr = 0.f, ssr = 0.f, sz = 0.f, ssz = 0.f;
        #pragma unroll
        for (int j = 0; j < 4; j++) {
            int col = c + j * 128;
            float hr = hgrow[col] + bhr[j];
            float hz = hgrow[512 + col] + bhz[j];
            hgn[j] = hgrow[1024 + col] + bhn[j];
            ar[j] = __bfloat162float(xgrow[col]) + hr;
            az[j] = __bfloat162float(xgrow[512 + col]) + hz;
            xn[j] = __bfloat162float(xgrow[1024 + col]);
            sr += ar[j]; ssr += ar[j] * ar[j];
            sz += az[j]; ssz += az[j] * az[j];
        }
        // reduce 4 scalars over the 128 threads of this sample (waves 2sid,2sid+1)
        #pragma unroll
        for (int off = 32; off; off >>= 1) {
            sr += __shfl_down(sr, off); ssr += __shfl_down(ssr, off);
            sz += __shfl_down(sz, off); ssz += __shfl_down(ssz, off);
        }
        if (lane == 0) { sc[w * 4] = sr; sc[w * 4 + 1] = ssr; sc[w * 4 + 2] = sz; sc[w * 4 + 3] = ssz; }
        __syncthreads();
        {
            int w0 = sid * 2;
            sr  = sc[w0 * 4]     + sc[(w0 + 1) * 4];
            ssr = sc[w0 * 4 + 1] + sc[(w0 + 1) * 4 + 1];
            sz  = sc[w0 * 4 + 2] + sc[(w0 + 1) * 4 + 2];
            ssz = sc[w0 * 4 + 3] + sc[(w0 + 1) * 4 + 3];
        }
        __syncthreads();
        float mr = sr * inv, vr = ssr * inv - mr * mr, rstd_r = rsqrtf(vr + 1e-5f);
        float mz = sz * inv, vz = ssz * inv - mz * mz, rstd_z = rsqrtf(vz + 1e-5f);
        float rg[4], zg[4], an[4];
        float sn = 0.f, ssn = 0.f;
        #pragma unroll
        for (int j = 0; j < 4; j++) {
            rg[j] = 1.f / (1.f + __expf(-((ar[j] - mr) * rstd_r * wr[j] + br_[j])));
            zg[j] = 1.f / (1.f + __expf(-((az[j] - mz) * rstd_z * wz[j] + bz_[j])));
            an[j] = xn[j] + rg[j] * hgn[j];
            sn += an[j]; ssn += an[j] * an[j];
        }
        #pragma unroll
        for (int off = 32; off; off >>= 1) {
            sn += __shfl_down(sn, off); ssn += __shfl_down(ssn, off);
        }
        if (lane == 0) { sc[w * 4] = sn; sc[w * 4 + 1] = ssn; }
        __syncthreads();
        {
            int w0 = sid * 2;
            sn  = sc[w0 * 4]     + sc[(w0 + 1) * 4];
            ssn = sc[w0 * 4 + 1] + sc[(w0 + 1) * 4 + 1];
        }
        __syncthreads();
        float mn = sn * inv, vn = ssn * inv - mn * mn, rstd_n = rsqrtf(vn + 1e-5f);
        float hnew[4];
        #pragma unroll
        for (int j = 0; j < 4; j++) {
            float ng = tanhf((an[j] - mn) * rstd_n * wn[j] + bn_[j]);
            hnew[j] = (1.f - zg[j]) * ng + zg[j] * hf[j];
            hf[j] = hnew[j];
            HB[b * H_ + c + j * 128] = __float2bfloat16(hnew[j]);
        }
        // ---- barrier B: all h_new slices visible ----
        __syncthreads();
        if (tid == 0) {
            __threadfence();
            __hip_atomic_fetch_add(&ctr[2 * t + 1], 1u, __ATOMIC_RELEASE, __HIP_MEMORY_SCOPE_AGENT);
            while (__hip_atomic_load(&ctr[2 * t + 1], __ATOMIC_ACQUIRE, __HIP_MEMORY_SCOPE_AGENT) < NBLK) {}
            __threadfence();
        }
        __syncthreads();
        // out rows (private to this block) — after barrier, overlaps next GEMM
        #pragma unroll
        for (int j = 0; j < 4; j++)
            out[((size_t)b * T_ + t) * H_ + c + j * 128] = hnew[j];
        if (t == T_ - 1) {
            #pragma unroll
            for (int j = 0; j < 4; j++)
                out[(size_t)B_ * T_ * H_ + b * H_ + c + j * 128] = hnew[j];
        }
    }
}

extern "C" void kernel_launch(void* const* d_in, const int* in_sizes, int n_in,
                              void* d_out, int out_size, void* d_ws, size_t ws_size,
                              hipStream_t stream)
{
    const float* x    = (const float*)d_in[0];
    const float* h    = (const float*)d_in[1];
    const float* w_ih = (const float*)d_in[2];
    const float* b_ih = (const float*)d_in[3];
    const float* w_hh = (const float*)d_in[4];
    const float* b_hh = (const float*)d_in[5];
    const float* lnrw = (const float*)d_in[6];
    const float* lnrb = (const float*)d_in[7];
    const float* lnzw = (const float*)d_in[8];
    const float* lnzb = (const float*)d_in[9];
    const float* lnnw = (const float*)d_in[10];
    const float* lnnb = (const float*)d_in[11];
    float* out = (float*)d_out;

    // ws layout (bytes):
    //   XG  bf16 [512][64][1536] = 100,663,296 @ 0
    //   HG  f32  [64][1536]      =     393,216 @ 100,663,296
    //   HB  bf16 [64][512]       =      65,536 @ 101,056,512
    //   CTR u32  [1024]          =       4,096 @ 101,122,048
    char* ws = (char*)d_ws;
    __hip_bfloat16* XG = (__hip_bfloat16*)ws;
    float*          HG = (float*)(ws + 100663296);
    __hip_bfloat16* HB = (__hip_bfloat16*)(ws + 101056512);
    unsigned int*  CTR = (unsigned int*)(ws + 101122048);

    k0_init<<<128, 256, 0, stream>>>(h, HB, CTR);
    k1_xgemm<<<3072, 256, 0, stream>>>(x, w_ih, b_ih, XG);
    k2_recur<<<NBLK, 512, 0, stream>>>(h, w_hh, b_hh,
        lnrw, lnrb, lnzw, lnzb, lnnw, lnnb, XG, HG, HB, CTR, out);
}